// Round 1
// baseline (398.047 us; speedup 1.0000x reference)
//
#include <hip/hip_runtime.h>
#include <cstdint>
#include <cstddef>

// ---------------------------------------------------------------------------
// KANAdaptiveFusion: fused = [bases(x) | silu(x)] @ W'^T ; LayerNorm over OUT.
//   B=16384, IN=1024, OUT=512, COEF=8 -> K' = 1024*8 + 1024 = 9216.
//   W'(o, i*8+k)      = spline_weight(o,i,k) * spline_scaler(o,i)   (bf16)
//   W'(o, 8192+i)     = base_weight(o,i)                            (bf16)
//   A'(b, i*8+k)      = basis_k(x[b,i])   (cubic B-spline, uniform knots)
//   A'(b, 8192+i)     = silu(x[b,i])
// Basis/silu computed on the fly while staging the A LDS tile (A' never hits
// HBM). W' precomputed into d_ws (9.4 MB). GEMM writes pre-LN fused to d_out;
// LN kernel normalizes in place.
// ---------------------------------------------------------------------------

#define BATCH    16384
#define IN_DIM   1024
#define OUT_DIM  512
#define K_SPLINE 8192
#define KTOT     9216
#define BM       128
#define BN       128
#define BK       64
#define NCHUNK        (KTOT / BK)      // 144
#define SPLINE_CHUNKS (K_SPLINE / BK)  // 128

typedef __attribute__((ext_vector_type(8))) short  short8;
typedef __attribute__((ext_vector_type(4))) float  f32x4;

static __device__ __forceinline__ unsigned short f2bf(float f) {
    // round-to-nearest-even f32 -> bf16 bits
    unsigned int u = __float_as_uint(f);
    unsigned int r = u + 0x7fffu + ((u >> 16) & 1u);
    return (unsigned short)(r >> 16);
}

// ---------------------------------------------------------------------------
// prep: build W' bf16 (OUT_DIM x KTOT, row-major) in workspace.
// one thread = 8 consecutive k' columns of one output row. 589824 threads.
// ---------------------------------------------------------------------------
__global__ void prep_w_kernel(const float* __restrict__ bw,
                              const float* __restrict__ sw,
                              const float* __restrict__ sc,
                              unsigned short* __restrict__ Wp) {
    int t = blockIdx.x * 256 + threadIdx.x;      // < 512 * 1152
    int o = t / 1152;
    int g = t - o * 1152;
    unsigned short o8[8];
    size_t dst;
    if (g < 1024) {                 // spline region: i = g, coefs 0..7
        float s = sc[(size_t)o * 1024 + g];
        const float* w = sw + ((size_t)o * 1024 + g) * 8;
        #pragma unroll
        for (int k = 0; k < 8; ++k) o8[k] = f2bf(w[k] * s);
        dst = (size_t)o * KTOT + (size_t)g * 8;
    } else {                        // base region: 8 i's per thread
        int i8 = (g - 1024) * 8;
        const float* w = bw + (size_t)o * 1024 + i8;
        #pragma unroll
        for (int k = 0; k < 8; ++k) o8[k] = f2bf(w[k]);
        dst = (size_t)o * KTOT + K_SPLINE + i8;
    }
    *reinterpret_cast<short8*>(Wp + dst) = *reinterpret_cast<const short8*>(o8);
}

// ---------------------------------------------------------------------------
// fused-basis bf16 MFMA GEMM. 128x128 tile, BK=64, 256 threads (4 waves,
// 2x2 wave grid, 64x64 per wave, 4x4 frags of 16x16x32).
// ---------------------------------------------------------------------------
__launch_bounds__(256)
__global__ void kan_gemm_kernel(const float* __restrict__ rgb,
                                const float* __restrict__ tac,
                                const unsigned short* __restrict__ Wp,
                                float* __restrict__ out) {
    __shared__ unsigned short At[BM][BK];   // 16 KB, k-contiguous
    __shared__ unsigned short Bt[BN][BK];   // 16 KB, k-contiguous (o rows)

    const int tid  = threadIdx.x;
    const int lane = tid & 63;
    const int wid  = tid >> 6;
    const int b0   = blockIdx.x * BM;
    const int n0   = blockIdx.y * BN;
    const int wm   = (wid & 1) * 64;
    const int wn   = (wid >> 1) * 64;

    f32x4 acc[4][4];
    #pragma unroll
    for (int m = 0; m < 4; ++m)
        #pragma unroll
        for (int n = 0; n < 4; ++n)
            acc[m][n] = (f32x4){0.f, 0.f, 0.f, 0.f};

    for (int kc = 0; kc < NCHUNK; ++kc) {
        // ---------------- stage A (computed on the fly) ----------------
        if (kc < SPLINE_CHUNKS) {
            // 8 input features per chunk; each thread handles 4 (row, i) pairs,
            // producing the 8 basis values (<=4 nonzero, scattered over zeros).
            int i0 = kc * 8;
            const float* xs = (i0 < 512) ? rgb : tac;
            int ic = (i0 < 512) ? i0 : (i0 - 512);
            #pragma unroll
            for (int rep = 0; rep < 4; ++rep) {
                int e  = tid + rep * 256;           // 0..1023
                int r  = e >> 3;
                int il = e & 7;
                float x = xs[(size_t)(b0 + r) * 512 + ic + il];
                unsigned short* dstp = &At[r][il * 8];
                short8 z = {0, 0, 0, 0, 0, 0, 0, 0};
                *reinterpret_cast<short8*>(dstp) = z;
                // interval index on the extended uniform knot grid
                // knots g[t] = -2.2 + 0.4*t, t = 0..11 ; 11 intervals
                float tpos = (x + 2.2f) * 2.5f;
                float fj   = floorf(tpos);
                int   j    = (int)fj;
                if (j >= 0 && j <= 10) {
                    float u  = tpos - fj;
                    float v  = 1.f - u;
                    float u2 = u * u;
                    float u3 = u2 * u;
                    const float c6 = 1.f / 6.f;
                    float n0v = v * v * v * c6;
                    float n1v = (3.f * u3 - 6.f * u2 + 4.f) * c6;
                    float n2v = (-3.f * u3 + 3.f * u2 + 3.f * u + 1.f) * c6;
                    float n3v = u3 * c6;
                    int base = j - 3;   // nonzero basis index range [j-3, j]
                    int t0 = base + 0; if (t0 >= 0 && t0 < 8) dstp[t0] = f2bf(n0v);
                    int t1 = base + 1; if (t1 >= 0 && t1 < 8) dstp[t1] = f2bf(n1v);
                    int t2 = base + 2; if (t2 >= 0 && t2 < 8) dstp[t2] = f2bf(n2v);
                    int t3 = base + 3; if (t3 >= 0 && t3 < 8) dstp[t3] = f2bf(n3v);
                }
            }
        } else {
            // base path: 64 features per chunk, A col = silu(x)
            int i0 = (kc - SPLINE_CHUNKS) * 64;
            const float* xs = (i0 < 512) ? rgb : tac;
            int ic = (i0 < 512) ? i0 : (i0 - 512);
            #pragma unroll
            for (int rep = 0; rep < 4; ++rep) {
                int gq = tid + rep * 256;           // 0..1023 groups of 8 cols
                int r  = gq >> 3;
                int c8 = (gq & 7) * 8;
                const float* xp = xs + (size_t)(b0 + r) * 512 + ic + c8;
                f32x4 x0 = *reinterpret_cast<const f32x4*>(xp);
                f32x4 x1 = *reinterpret_cast<const f32x4*>(xp + 4);
                unsigned short o8[8];
                #pragma unroll
                for (int q = 0; q < 4; ++q) {
                    float a = x0[q];
                    o8[q]     = f2bf(a / (1.f + __expf(-a)));
                    float b = x1[q];
                    o8[q + 4] = f2bf(b / (1.f + __expf(-b)));
                }
                *reinterpret_cast<short8*>(&At[r][c8]) =
                    *reinterpret_cast<const short8*>(o8);
            }
        }

        // ---------------- stage B: global_load_lds width=16 ----------------
        {
            int k0g = kc * BK;
            #pragma unroll
            for (int rp = 0; rp < 4; ++rp) {
                int row0 = rp * 32 + wid * 8;   // wave-uniform LDS base
                const unsigned short* gp =
                    Wp + (size_t)(n0 + row0 + (lane >> 3)) * KTOT + k0g + (lane & 7) * 8;
                __builtin_amdgcn_global_load_lds(
                    (const __attribute__((address_space(1))) unsigned int*)gp,
                    (__attribute__((address_space(3))) unsigned int*)&Bt[row0][0],
                    16, 0, 0);
            }
        }
        asm volatile("s_waitcnt vmcnt(0) lgkmcnt(0)" ::: "memory");
        __syncthreads();

        // ---------------- MFMA: 2 k-substeps of 32 ----------------
        #pragma unroll
        for (int ks = 0; ks < 2; ++ks) {
            int ko = ks * 32 + (lane >> 4) * 8;
            short8 af[4], bfr[4];
            #pragma unroll
            for (int m = 0; m < 4; ++m)
                af[m] = *reinterpret_cast<const short8*>(&At[wm + m * 16 + (lane & 15)][ko]);
            #pragma unroll
            for (int n = 0; n < 4; ++n)
                bfr[n] = *reinterpret_cast<const short8*>(&Bt[wn + n * 16 + (lane & 15)][ko]);
            #pragma unroll
            for (int m = 0; m < 4; ++m)
                #pragma unroll
                for (int n = 0; n < 4; ++n)
                    acc[m][n] = __builtin_amdgcn_mfma_f32_16x16x32_bf16(
                        af[m], bfr[n], acc[m][n], 0, 0, 0);
        }
        __syncthreads();
    }

    // ---------------- epilogue: store pre-LN fused to d_out ----------------
    #pragma unroll
    for (int m = 0; m < 4; ++m) {
        int row = b0 + wm + m * 16 + ((lane >> 4) << 2);
        #pragma unroll
        for (int n = 0; n < 4; ++n) {
            int col = n0 + wn + n * 16 + (lane & 15);
            #pragma unroll
            for (int jj = 0; jj < 4; ++jj)
                out[(size_t)(row + jj) * OUT_DIM + col] = acc[m][n][jj];
        }
    }
}

// ---------------------------------------------------------------------------
// LayerNorm over OUT=512, in place on d_out. One wave per row.
// ---------------------------------------------------------------------------
__global__ void ln_kernel(float* __restrict__ io,
                          const float* __restrict__ gamma,
                          const float* __restrict__ beta) {
    int row  = blockIdx.x * 4 + (threadIdx.x >> 6);
    int lane = threadIdx.x & 63;
    float* p = io + (size_t)row * OUT_DIM;
    f32x4 v0 = *reinterpret_cast<const f32x4*>(p + lane * 4);
    f32x4 v1 = *reinterpret_cast<const f32x4*>(p + 256 + lane * 4);
    float s  = 0.f, ss = 0.f;
    #pragma unroll
    for (int q = 0; q < 4; ++q) {
        s  += v0[q] + v1[q];
        ss += v0[q] * v0[q] + v1[q] * v1[q];
    }
    #pragma unroll
    for (int off = 1; off < 64; off <<= 1) {
        s  += __shfl_xor(s, off);
        ss += __shfl_xor(ss, off);
    }
    float mu  = s * (1.f / 512.f);
    float var = ss * (1.f / 512.f) - mu * mu;
    float rs  = rsqrtf(var + 1e-5f);
    f32x4 g0 = *reinterpret_cast<const f32x4*>(gamma + lane * 4);
    f32x4 g1 = *reinterpret_cast<const f32x4*>(gamma + 256 + lane * 4);
    f32x4 b0 = *reinterpret_cast<const f32x4*>(beta + lane * 4);
    f32x4 b1 = *reinterpret_cast<const f32x4*>(beta + 256 + lane * 4);
    f32x4 r0, r1;
    #pragma unroll
    for (int q = 0; q < 4; ++q) {
        r0[q] = (v0[q] - mu) * rs * g0[q] + b0[q];
        r1[q] = (v1[q] - mu) * rs * g1[q] + b1[q];
    }
    *reinterpret_cast<f32x4*>(p + lane * 4)       = r0;
    *reinterpret_cast<f32x4*>(p + 256 + lane * 4) = r1;
}

// ---------------------------------------------------------------------------
extern "C" void kernel_launch(void* const* d_in, const int* in_sizes, int n_in,
                              void* d_out, int out_size, void* d_ws, size_t ws_size,
                              hipStream_t stream) {
    const float* rgb   = (const float*)d_in[0];
    const float* tac   = (const float*)d_in[1];
    const float* bw    = (const float*)d_in[2];
    const float* sw    = (const float*)d_in[3];
    const float* sc    = (const float*)d_in[4];
    const float* gamma = (const float*)d_in[5];
    const float* beta  = (const float*)d_in[6];
    float* out = (float*)d_out;
    unsigned short* Wp = (unsigned short*)d_ws;   // 512*9216*2 = 9.4 MB

    prep_w_kernel<<<2304, 256, 0, stream>>>(bw, sw, sc, Wp);

    dim3 g(BATCH / BM, OUT_DIM / BN);             // (128, 4)
    kan_gemm_kernel<<<g, 256, 0, stream>>>(rgb, tac, Wp, out);

    ln_kernel<<<BATCH / 4, 256, 0, stream>>>(out, gamma, beta);
}